// Round 5
// baseline (451.040 us; speedup 1.0000x reference)
//
#include <hip/hip_runtime.h>
#include <hip/hip_bf16.h>

#define EPS 1e-5f
#define SLOPE 0.2f

#define NF 16      // frames = T-1
#define NBATCH 16  // batch B
#define NC 512     // channels C (= GEMM N and K)
#define NHW 256    // H*W
#define ND 256     // cond dim D
#define K2 768     // C + D (conv2_w row stride)
#define MF 4096    // per-frame GEMM M = B*HW
#define FRAME_ELEMS ((size_t)MF * NC)   // 2,097,152

typedef __attribute__((ext_vector_type(8))) short short8;
typedef __attribute__((ext_vector_type(4))) float float4v;

__device__ __forceinline__ float lrelu(float v) { return v >= 0.f ? v : SLOPE * v; }
__device__ __forceinline__ float b2f(ushort u) { union { float f; uint i; } x; x.i = ((uint)u) << 16; return x.f; }
__device__ __forceinline__ ushort f2b(float f) {
  uint i = __float_as_uint(f);
  return (ushort)((i + 0x7FFFu + ((i >> 16) & 1u)) >> 16);
}

// ---------------- fused prep: weights->bf16 + sent ------------------------------
// blocks 0..1023: convert w1 (full) and w2 (first 512 cols) to bf16
// block 1024: sent = leaky(bn(cond @ lin_w.T + lin_b))  [B,D]
__global__ __launch_bounds__(256) void k_pre(
    const float* __restrict__ w1, const float* __restrict__ w2,
    const float* __restrict__ cond, const float* __restrict__ lin_w,
    const float* __restrict__ lin_b, const float* __restrict__ gam,
    const float* __restrict__ bet,
    ushort* __restrict__ w1b, ushort* __restrict__ w2b,
    float* __restrict__ sent) {
  int bx = blockIdx.x, t = threadIdx.x;
  if (bx < 1024) {
    int i = bx * 256 + t;
    w1b[i] = f2b(w1[i]);
    int o = i >> 9, c = i & 511;
    w2b[i] = f2b(w2[(size_t)o * K2 + c]);
    return;
  }
  // sent (one block, 256 threads, one channel d each)
  int d = t;
  float acc[NBATCH];
  float bias = lin_b[d];
#pragma unroll
  for (int b = 0; b < NBATCH; ++b) acc[b] = bias;
  for (int k = 0; k < ND; ++k) {
    float w = lin_w[d * ND + k];
#pragma unroll
    for (int b = 0; b < NBATCH; ++b) acc[b] = fmaf(cond[b * ND + k], w, acc[b]);
  }
  float mu = 0.f;
#pragma unroll
  for (int b = 0; b < NBATCH; ++b) mu += acc[b];
  mu *= (1.f / NBATCH);
  float var = 0.f;
#pragma unroll
  for (int b = 0; b < NBATCH; ++b) { float x = acc[b] - mu; var = fmaf(x, x, var); }
  var *= (1.f / NBATCH);
  float sc = rsqrtf(var + EPS) * gam[d];
  float sh = bet[d] - mu * sc;
#pragma unroll
  for (int b = 0; b < NBATCH; ++b) sent[b * ND + d] = lrelu(fmaf(acc[b], sc, sh));
}

// ---------------- motions: diff + transpose + cvt; bias2 folded at x==32 ---------
__global__ __launch_bounds__(256) void k_mot(
    const float* __restrict__ xbar, ushort* __restrict__ mot, int f0, int nb,
    const float* __restrict__ sent, const float* __restrict__ w2,
    float* __restrict__ bias2) {
  int t = threadIdx.x;
  if (blockIdx.x == 32) {
    // bias2[b][o] = sum_d sent[b,d] * w2[o, 512+d]  (2 blocks: y==0,1; z==0)
    if (blockIdx.z != 0 || blockIdx.y >= 2) return;
    int o = blockIdx.y * 256 + t;
    float acc[NBATCH];
#pragma unroll
    for (int b = 0; b < NBATCH; ++b) acc[b] = 0.f;
    for (int d = 0; d < ND; ++d) {
      float w = w2[(size_t)o * K2 + NC + d];
#pragma unroll
      for (int b = 0; b < NBATCH; ++b) acc[b] = fmaf(sent[b * ND + d], w, acc[b]);
    }
#pragma unroll
    for (int b = 0; b < NBATCH; ++b) bias2[b * NC + o] = acc[b];
    return;
  }

  __shared__ float T[64][65];
  int b = blockIdx.y;
  int hw0 = (blockIdx.x & 3) * 64;
  int c0 = (blockIdx.x >> 2) * 64;
  int w = t >> 6, l = t & 63;
  int fs = blockIdx.z * 8;
  int fe = fs + 8 < nb ? fs + 8 : nb;

  const float* xp = xbar + ((size_t)(f0 + fs) * NBATCH + b) * (NC * NHW) + hw0 + l;
  float prev[16];
#pragma unroll
  for (int k = 0; k < 16; ++k) prev[k] = xp[(size_t)(c0 + 4 * k + w) * NHW];

  for (int fr = fs; fr < fe; ++fr) {
    const float* xc = xbar + ((size_t)(f0 + fr + 1) * NBATCH + b) * (NC * NHW) + hw0 + l;
    float cur[16];
#pragma unroll
    for (int k = 0; k < 16; ++k) cur[k] = xc[(size_t)(c0 + 4 * k + w) * NHW];
#pragma unroll
    for (int k = 0; k < 16; ++k) T[4 * k + w][l] = cur[k] - prev[k];
    __syncthreads();
    ushort* mp = mot + ((size_t)fr * MF + b * NHW + hw0) * NC + c0;
#pragma unroll
    for (int k = 0; k < 16; ++k) mp[(size_t)(4 * k + w) * NC + l] = f2b(T[l][4 * k + w]);
    __syncthreads();
#pragma unroll
    for (int k = 0; k < 16; ++k) prev[k] = cur[k];
  }
}

// ---------------- direct-from-L2 MFMA GEMM (no LDS staging, no barriers) ---------
// block: 64m x 256n, 4 waves (one 64x64 n-quarter each), BK=32, reg ping-pong
// prefetch. A is [m][k] bf16 (L2/L3-resident), W is [n][k] bf16 (L2-resident).
// Epilogue: optional bias add, partial BN stats, LDS-transpose coalesced store.
template <int BIAS>
__global__ __launch_bounds__(256, 3) void k_gemmd(
    const ushort* __restrict__ A, const ushort* __restrict__ W,
    const float* __restrict__ bias2, ushort* __restrict__ H,
    float2* __restrict__ part) {
  __shared__ ushort ep_lds[4][1088];  // 16 x 68 per wave (epilogue only)
  int t = threadIdx.x, w = t >> 6, l = t & 63;
  int g = blockIdx.z, m0 = blockIdx.x * 64, n0 = blockIdx.y * 256 + w * 64;
  int ar = l & 15, kb = (l >> 4) * 8;

  const ushort* Ag = A + ((size_t)g * MF + m0 + ar) * NC + kb;
  const ushort* Wg = W + ((size_t)n0 + ar) * NC + kb;

  float4v acc[4][4];
#pragma unroll
  for (int i = 0; i < 4; ++i)
#pragma unroll
    for (int j = 0; j < 4; ++j) acc[i][j] = (float4v)0.f;

#define LOADF(aR, bR, c0)                                             \
  do {                                                                \
    _Pragma("unroll") for (int i = 0; i < 4; ++i)                     \
        aR[i] = *(const short8*)&Ag[(size_t)(i * 16) * NC + (c0)];    \
    _Pragma("unroll") for (int j = 0; j < 4; ++j)                     \
        bR[j] = *(const short8*)&Wg[(size_t)(j * 16) * NC + (c0)];    \
  } while (0)

#define MFMA_SET(aR, bR)                                              \
  do {                                                                \
    _Pragma("unroll") for (int i = 0; i < 4; ++i)                     \
      _Pragma("unroll") for (int j = 0; j < 4; ++j)                   \
          acc[i][j] = __builtin_amdgcn_mfma_f32_16x16x32_bf16(        \
              aR[i], bR[j], acc[i][j], 0, 0, 0);                      \
  } while (0)

  short8 a0[4], b0[4], a1[4], b1[4];
  LOADF(a0, b0, 0);
#pragma unroll
  for (int kt = 0; kt < 16; ++kt) {
    if ((kt & 1) == 0) {
      if (kt < 15) LOADF(a1, b1, (kt + 1) * 32);
      MFMA_SET(a0, b0);
    } else {
      if (kt < 15) LOADF(a0, b0, (kt + 1) * 32);
      MFMA_SET(a1, b1);
    }
  }
#undef LOADF
#undef MFMA_SET

  // fold bias, accumulate per-channel partial stats
  float bz[4];
#pragma unroll
  for (int fn = 0; fn < 4; ++fn)
    bz[fn] = BIAS ? bias2[(m0 >> 8) * NC + n0 + fn * 16 + (l & 15)] : 0.f;

  float sv[4], qv[4];
#pragma unroll
  for (int fn = 0; fn < 4; ++fn) {
    float s = 0.f, q = 0.f;
#pragma unroll
    for (int fm = 0; fm < 4; ++fm)
#pragma unroll
      for (int j = 0; j < 4; ++j) {
        float v = acc[fm][fn][j] + bz[fn];
        acc[fm][fn][j] = v;
        s += v;
        q = fmaf(v, v, q);
      }
    s += __shfl_xor(s, 16); s += __shfl_xor(s, 32);
    q += __shfl_xor(q, 16); q += __shfl_xor(q, 32);
    sv[fn] = s; qv[fn] = q;
  }
  if (l < 16) {
    int mb = blockIdx.x;  // 64-row chunk id (0..63)
    float2* pp = part + ((size_t)g * 64 + mb) * NC + n0 + l;
#pragma unroll
    for (int fn = 0; fn < 4; ++fn) pp[fn * 16] = make_float2(sv[fn], qv[fn]);
  }

  // per-wave LDS transpose for coalesced [m][o] bf16 stores
  ushort* ep = &ep_lds[w][0];
  ushort* Hg = H + ((size_t)g * MF + m0) * NC + n0;
#pragma unroll
  for (int fm = 0; fm < 4; ++fm) {
#pragma unroll
    for (int fn = 0; fn < 4; ++fn)
#pragma unroll
      for (int j = 0; j < 4; ++j)
        ep[((l >> 4) * 4 + j) * 68 + fn * 16 + (l & 15)] = f2b(acc[fm][fn][j]);
#pragma unroll
    for (int h = 0; h < 2; ++h) {
      int r = h * 8 + (l >> 3), sl = l & 7;
      short8 v = *(const short8*)&ep[r * 68 + sl * 8];
      *(short8*)&Hg[(size_t)(fm * 16 + r) * NC + sl * 8] = v;
    }
  }
}

// ---------------- stats finalize: (scale, shift) per (g,o) from 64 partials ------
__global__ __launch_bounds__(256) void k_stats2(
    const float2* __restrict__ part, const float* __restrict__ gam,
    const float* __restrict__ bet, float2* __restrict__ st) {
  int bi = blockIdx.x;
  int g = bi >> 1;
  int o = (bi & 1) * 256 + threadIdx.x;
  float s = 0.f, q = 0.f;
#pragma unroll
  for (int mb = 0; mb < 64; ++mb) {
    float2 v = part[((size_t)g * 64 + mb) * NC + o];
    s += v.x;
    q += v.y;
  }
  float mu = s * (1.f / 4096.f);
  float var = q * (1.f / 4096.f) - mu * mu;
  float sc = rsqrtf(var + EPS) * gam[o];
  st[g * NC + o] = make_float2(sc, bet[o] - mu * sc);
}

// ---------------- act: a1 = bf16(lrelu(h1*sc+sh)) --------------------------------
__global__ __launch_bounds__(256) void k_act(
    const ushort* __restrict__ h1, const float2* __restrict__ st,
    ushort* __restrict__ a1) {
  int g = blockIdx.z;
  size_t i0 = ((size_t)blockIdx.x * 256 + threadIdx.x) * 8;
  int o0 = (int)(i0 & 511);
  const ushort* src = h1 + (size_t)g * FRAME_ELEMS + i0;
  ushort* dst = a1 + (size_t)g * FRAME_ELEMS + i0;
  short8 v = *(const short8*)src;
  short8 r;
#pragma unroll
  for (int e = 0; e < 8; ++e) {
    float2 ss = st[g * NC + o0 + e];
    float x = fmaf(b2f((ushort)v[e]), ss.x, ss.y);
    r[e] = (short)f2b(lrelu(x));
  }
  *(short8*)dst = r;
}

// ---------------- conv3: 2x2 stride-2, with inline bn+leaky ----------------------
__global__ __launch_bounds__(256) void k_conv3(
    const ushort* __restrict__ h2, const float2* __restrict__ st2,
    const float* __restrict__ w3, float* __restrict__ out, int f0) {
  int g = blockIdx.z;
  int b = blockIdx.x;
  int t = threadIdx.x;
  int oi = t >> 2;  // output pixel 0..63
  int cs = t & 3;   // channel quarter
  int y = oi >> 3, x = oi & 7;
  const ushort* base = h2 + ((size_t)g * MF + b * NHW) * NC;
  int m00 = (2 * y) * 16 + 2 * x;
  float acc = 0.f;
  for (int c8 = cs * 128; c8 < cs * 128 + 128; c8 += 8) {
    short8 v0 = *(const short8*)&base[(size_t)(m00 + 0) * NC + c8];
    short8 v1 = *(const short8*)&base[(size_t)(m00 + 1) * NC + c8];
    short8 v2 = *(const short8*)&base[(size_t)(m00 + 16) * NC + c8];
    short8 v3 = *(const short8*)&base[(size_t)(m00 + 17) * NC + c8];
#pragma unroll
    for (int e = 0; e < 8; ++e) {
      float2 ss = st2[g * NC + c8 + e];
      float4 wv = ((const float4*)w3)[c8 + e];
      acc = fmaf(lrelu(fmaf(b2f((ushort)v0[e]), ss.x, ss.y)), wv.x, acc);
      acc = fmaf(lrelu(fmaf(b2f((ushort)v1[e]), ss.x, ss.y)), wv.y, acc);
      acc = fmaf(lrelu(fmaf(b2f((ushort)v2[e]), ss.x, ss.y)), wv.z, acc);
      acc = fmaf(lrelu(fmaf(b2f((ushort)v3[e]), ss.x, ss.y)), wv.w, acc);
    }
  }
  acc += __shfl_xor(acc, 1);
  acc += __shfl_xor(acc, 2);
  if (cs == 0) out[((size_t)(f0 + g) * NBATCH + b) * 64 + oi] = acc;
}

extern "C" void kernel_launch(void* const* d_in, const int* in_sizes, int n_in,
                              void* d_out, int out_size, void* d_ws, size_t ws_size,
                              hipStream_t stream) {
  const float* cond = (const float*)d_in[0];
  const float* xbar = (const float*)d_in[1];
  const float* lin_w = (const float*)d_in[2];
  const float* lin_b = (const float*)d_in[3];
  const float* bnsg = (const float*)d_in[4];
  const float* bnsb = (const float*)d_in[5];
  const float* w1 = (const float*)d_in[6];
  const float* bn1g = (const float*)d_in[7];
  const float* bn1b = (const float*)d_in[8];
  const float* w2 = (const float*)d_in[9];
  const float* bn2g = (const float*)d_in[10];
  const float* bn2b = (const float*)d_in[11];
  const float* w3 = (const float*)d_in[12];
  float* out = (float*)d_out;

  char* p = (char*)d_ws;
  float* sent = (float*)p;    p += ((NBATCH * ND * 4 + 255) & ~255);
  float* bias2 = (float*)p;   p += ((NBATCH * NC * 4 + 255) & ~255);
  float2* st1 = (float2*)p;   p += ((NF * NC * 8 + 255) & ~255);
  float2* st2 = (float2*)p;   p += ((NF * NC * 8 + 255) & ~255);
  float2* part = (float2*)p;  p += (((size_t)NF * 64 * NC * 8 + 255) & ~255);
  ushort* w1b = (ushort*)p;   p += ((NC * NC * 2 + 255) & ~255);
  ushort* w2b = (ushort*)p;   p += ((NC * NC * 2 + 255) & ~255);
  size_t used = (size_t)(p - (char*)d_ws);
  const size_t frame_bytes = FRAME_ELEMS * 2;  // 4.19 MB bf16
  size_t rem = ws_size > used ? ws_size - used : 0;
  int FB = (int)(rem / (3 * frame_bytes));
  if (FB < 1) FB = 1;
  if (FB > NF) FB = NF;
  ushort* bufA = (ushort*)p;                       // mot, then a1 (after gemm1)
  ushort* bufB = bufA + (size_t)FB * FRAME_ELEMS;  // h1
  ushort* bufC = bufB + (size_t)FB * FRAME_ELEMS;  // h2

  k_pre<<<1025, 256, 0, stream>>>(w1, w2, cond, lin_w, lin_b, bnsg, bnsb,
                                  w1b, w2b, sent);

  for (int f0 = 0; f0 < NF; f0 += FB) {
    int nb = (NF - f0) < FB ? (NF - f0) : FB;
    int ngrp = (nb + 7) / 8;
    k_mot<<<dim3(33, NBATCH, ngrp), 256, 0, stream>>>(xbar, bufA, f0, nb,
                                                      sent, w2, bias2);
    k_gemmd<0><<<dim3(64, 2, nb), 256, 0, stream>>>(bufA, w1b, nullptr, bufB, part);
    k_stats2<<<2 * nb, 256, 0, stream>>>(part, bn1g, bn1b, st1);
    k_act<<<dim3(1024, 1, nb), 256, 0, stream>>>(bufB, st1, bufA);
    k_gemmd<1><<<dim3(64, 2, nb), 256, 0, stream>>>(bufA, w2b, bias2, bufC, part);
    k_stats2<<<2 * nb, 256, 0, stream>>>(part, bn2g, bn2b, st2);
    k_conv3<<<dim3(NBATCH, 1, nb), 256, 0, stream>>>(bufC, st2, w3, out, f0);
  }
}

// Round 6
// 283.566 us; speedup vs baseline: 1.5906x; 1.5906x over previous
//
#include <hip/hip_runtime.h>
#include <hip/hip_bf16.h>

#define EPS 1e-5f
#define SLOPE 0.2f

#define NF 16      // frames = T-1
#define NBATCH 16  // batch B
#define NC 512     // channels C (= GEMM N and K)
#define NHW 256    // H*W
#define ND 256     // cond dim D
#define K2 768     // C + D (conv2_w row stride)
#define MF 4096    // per-frame GEMM M = B*HW
#define FRAME_ELEMS ((size_t)MF * NC)   // 2,097,152

typedef __attribute__((ext_vector_type(8))) short short8;
typedef __attribute__((ext_vector_type(4))) float float4v;

__device__ __forceinline__ float lrelu(float v) { return v >= 0.f ? v : SLOPE * v; }
__device__ __forceinline__ float b2f(ushort u) { union { float f; uint i; } x; x.i = ((uint)u) << 16; return x.f; }
__device__ __forceinline__ ushort f2b(float f) {
  uint i = __float_as_uint(f);
  return (ushort)((i + 0x7FFFu + ((i >> 16) & 1u)) >> 16);
}
__device__ __forceinline__ void gl16(const ushort* g, ushort* l) {
  __builtin_amdgcn_global_load_lds(
      (const __attribute__((address_space(1))) unsigned int*)g,
      (__attribute__((address_space(3))) unsigned int*)l, 16, 0, 0);
}

// ---------------- fused prep: weights->bf16 + sent ------------------------------
__global__ __launch_bounds__(256) void k_pre(
    const float* __restrict__ w1, const float* __restrict__ w2,
    const float* __restrict__ cond, const float* __restrict__ lin_w,
    const float* __restrict__ lin_b, const float* __restrict__ gam,
    const float* __restrict__ bet,
    ushort* __restrict__ w1b, ushort* __restrict__ w2b,
    float* __restrict__ sent) {
  int bx = blockIdx.x, t = threadIdx.x;
  if (bx < 1024) {
    int i = bx * 256 + t;
    w1b[i] = f2b(w1[i]);
    int o = i >> 9, c = i & 511;
    w2b[i] = f2b(w2[(size_t)o * K2 + c]);
    return;
  }
  int d = t;
  float acc[NBATCH];
  float bias = lin_b[d];
#pragma unroll
  for (int b = 0; b < NBATCH; ++b) acc[b] = bias;
  for (int k = 0; k < ND; ++k) {
    float w = lin_w[d * ND + k];
#pragma unroll
    for (int b = 0; b < NBATCH; ++b) acc[b] = fmaf(cond[b * ND + k], w, acc[b]);
  }
  float mu = 0.f;
#pragma unroll
  for (int b = 0; b < NBATCH; ++b) mu += acc[b];
  mu *= (1.f / NBATCH);
  float var = 0.f;
#pragma unroll
  for (int b = 0; b < NBATCH; ++b) { float x = acc[b] - mu; var = fmaf(x, x, var); }
  var *= (1.f / NBATCH);
  float sc = rsqrtf(var + EPS) * gam[d];
  float sh = bet[d] - mu * sc;
#pragma unroll
  for (int b = 0; b < NBATCH; ++b) sent[b * ND + d] = lrelu(fmaf(acc[b], sc, sh));
}

// ---------------- motions: diff + transpose + cvt; bias2 folded at x==32 ---------
__global__ __launch_bounds__(256) void k_mot(
    const float* __restrict__ xbar, ushort* __restrict__ mot, int f0, int nb,
    const float* __restrict__ sent, const float* __restrict__ w2,
    float* __restrict__ bias2) {
  int t = threadIdx.x;
  if (blockIdx.x == 32) {
    if (blockIdx.z != 0 || blockIdx.y >= 2) return;
    int o = blockIdx.y * 256 + t;
    float acc[NBATCH];
#pragma unroll
    for (int b = 0; b < NBATCH; ++b) acc[b] = 0.f;
    for (int d = 0; d < ND; ++d) {
      float w = w2[(size_t)o * K2 + NC + d];
#pragma unroll
      for (int b = 0; b < NBATCH; ++b) acc[b] = fmaf(sent[b * ND + d], w, acc[b]);
    }
#pragma unroll
    for (int b = 0; b < NBATCH; ++b) bias2[b * NC + o] = acc[b];
    return;
  }

  __shared__ float T[64][65];
  int b = blockIdx.y;
  int hw0 = (blockIdx.x & 3) * 64;
  int c0 = (blockIdx.x >> 2) * 64;
  int w = t >> 6, l = t & 63;
  int fs = blockIdx.z * 8;
  int fe = fs + 8 < nb ? fs + 8 : nb;

  const float* xp = xbar + ((size_t)(f0 + fs) * NBATCH + b) * (NC * NHW) + hw0 + l;
  float prev[16];
#pragma unroll
  for (int k = 0; k < 16; ++k) prev[k] = xp[(size_t)(c0 + 4 * k + w) * NHW];

  for (int fr = fs; fr < fe; ++fr) {
    const float* xc = xbar + ((size_t)(f0 + fr + 1) * NBATCH + b) * (NC * NHW) + hw0 + l;
    float cur[16];
#pragma unroll
    for (int k = 0; k < 16; ++k) cur[k] = xc[(size_t)(c0 + 4 * k + w) * NHW];
#pragma unroll
    for (int k = 0; k < 16; ++k) T[4 * k + w][l] = cur[k] - prev[k];
    __syncthreads();
    ushort* mp = mot + ((size_t)fr * MF + b * NHW + hw0) * NC + c0;
#pragma unroll
    for (int k = 0; k < 16; ++k) mp[(size_t)(4 * k + w) * NC + l] = f2b(T[l][4 * k + w]);
    __syncthreads();
#pragma unroll
    for (int k = 0; k < 16; ++k) prev[k] = cur[k];
  }
}

// ---------------- 256x256 8-wave MFMA GEMM, counted-vmcnt dbuf pipeline ----------
// BM=BN=256, BK=64, 8 waves (2M x 4N), per-wave 128x64 output.
// LDS: 2 bufs x (A 256x64 + B 256x64) bf16 = 128 KB. XOR cb-swizzle both sides.
// Pipeline: while computing K-tile t (buf t&1), K-tile t+1 is landing and t+2 is
// issued after the buf-free barrier; vmcnt(8) (never 0 mid-loop) gates reuse.
template <int BIAS>
__global__ __launch_bounds__(512, 2) void k_gemm8(
    const ushort* __restrict__ A, const ushort* __restrict__ W,
    const float* __restrict__ bias2, ushort* __restrict__ H,
    float2* __restrict__ part) {
  __shared__ ushort lds[65536];  // [buf][A:16384|B:16384]
  const int t = threadIdx.x, w = t >> 6, l = t & 63;
  const int g = blockIdx.z, bx = blockIdx.x, ny = blockIdx.y;
  const int m0 = bx * 256, n0 = ny * 256;
  const int wr = w >> 2, wc = w & 3;

  const ushort* Ag = A + (size_t)g * FRAME_ELEMS + (size_t)m0 * NC;
  const ushort* Wg = W + (size_t)n0 * NC;

  // staging: 4 units/thread/array; unit u: row u>>3, phys cb u&7 holds logical
  // cb (u&7)^(row&7)  (pre-swizzled global source, linear LDS dest)
  size_t goff[4];
  int loff[4];
#pragma unroll
  for (int q = 0; q < 4; ++q) {
    int u = w * 256 + q * 64 + l;
    int row = u >> 3, cb = (u & 7) ^ (row & 7);
    goff[q] = (size_t)row * NC + cb * 8;
    loff[q] = u * 8;
  }

#define STAGE8(t_, b_)                                               \
  do {                                                               \
    const int k0_ = (t_) * 64;                                       \
    _Pragma("unroll") for (int q = 0; q < 4; ++q)                    \
        gl16(Ag + goff[q] + k0_, &lds[(b_) * 32768 + loff[q]]);      \
    _Pragma("unroll") for (int q = 0; q < 4; ++q)                    \
        gl16(Wg + goff[q] + k0_, &lds[(b_) * 32768 + 16384 + loff[q]]); \
  } while (0)

  // frag-read swizzled k-slot: logical cb = kk*4 + (l>>4), phys = ^ (row&7)
  // row & 7 == l & 7 for all frag rows (row = 16*frag + (l&15))
  int slot[2];
#pragma unroll
  for (int kk = 0; kk < 2; ++kk) slot[kk] = (((kk * 4 + (l >> 4)) ^ (l & 7)) * 8);

  float4v acc[8][4];
#pragma unroll
  for (int i = 0; i < 8; ++i)
#pragma unroll
    for (int j = 0; j < 4; ++j) acc[i][j] = (float4v)0.f;

  STAGE8(0, 0);
  STAGE8(1, 1);
  asm volatile("s_waitcnt vmcnt(8)" ::: "memory");
  __builtin_amdgcn_sched_barrier(0);
  __builtin_amdgcn_s_barrier();
  __builtin_amdgcn_sched_barrier(0);

#pragma unroll
  for (int kt = 0; kt < 8; ++kt) {
    const int b = kt & 1;
    const ushort* la = &lds[b * 32768];
    const ushort* lb = la + 16384;
    short8 bf[4][2], af[4][2];
    // ---- phase A: B frags + A m-half0 frags, 32 MFMA ----
#pragma unroll
    for (int fn = 0; fn < 4; ++fn) {
      int r = wc * 64 + fn * 16 + (l & 15);
#pragma unroll
      for (int kk = 0; kk < 2; ++kk)
        bf[fn][kk] = *(const short8*)&lb[r * 64 + slot[kk]];
    }
#pragma unroll
    for (int fm = 0; fm < 4; ++fm) {
      int r = wr * 128 + fm * 16 + (l & 15);
#pragma unroll
      for (int kk = 0; kk < 2; ++kk)
        af[fm][kk] = *(const short8*)&la[r * 64 + slot[kk]];
    }
    asm volatile("s_waitcnt lgkmcnt(0)" ::: "memory");
    __builtin_amdgcn_sched_barrier(0);
    __builtin_amdgcn_s_setprio(1);
#pragma unroll
    for (int kk = 0; kk < 2; ++kk)
#pragma unroll
      for (int fm = 0; fm < 4; ++fm)
#pragma unroll
        for (int fn = 0; fn < 4; ++fn)
          acc[fm][fn] = __builtin_amdgcn_mfma_f32_16x16x32_bf16(
              af[fm][kk], bf[fn][kk], acc[fm][fn], 0, 0, 0);
    __builtin_amdgcn_s_setprio(0);
    // ---- phase B: A m-half1 frags; free buf -> stage t+2; 32 MFMA ----
#pragma unroll
    for (int fm = 0; fm < 4; ++fm) {
      int r = wr * 128 + 64 + fm * 16 + (l & 15);
#pragma unroll
      for (int kk = 0; kk < 2; ++kk)
        af[fm][kk] = *(const short8*)&la[r * 64 + slot[kk]];
    }
    asm volatile("s_waitcnt lgkmcnt(0)" ::: "memory");
    __builtin_amdgcn_sched_barrier(0);
    __builtin_amdgcn_s_barrier();   // all waves done reading buf b
    __builtin_amdgcn_sched_barrier(0);
    if (kt < 6) STAGE8(kt + 2, b);
    __builtin_amdgcn_s_setprio(1);
#pragma unroll
    for (int kk = 0; kk < 2; ++kk)
#pragma unroll
      for (int fm = 0; fm < 4; ++fm)
#pragma unroll
        for (int fn = 0; fn < 4; ++fn)
          acc[fm + 4][fn] = __builtin_amdgcn_mfma_f32_16x16x32_bf16(
              af[fm][kk], bf[fn][kk], acc[fm + 4][fn], 0, 0, 0);
    __builtin_amdgcn_s_setprio(0);
    if (kt < 7) {
      if (kt < 6) asm volatile("s_waitcnt vmcnt(8)" ::: "memory");  // t+1 landed
      else        asm volatile("s_waitcnt vmcnt(0)" ::: "memory");  // last: drain
      __builtin_amdgcn_sched_barrier(0);
      __builtin_amdgcn_s_barrier();
      __builtin_amdgcn_sched_barrier(0);
    }
  }
#undef STAGE8

  // ---- epilogue: bias fold, partial BN stats, LDS-transpose bf16 store ----
  __builtin_amdgcn_sched_barrier(0);
  __builtin_amdgcn_s_barrier();   // LDS reuse safe
  __builtin_amdgcn_sched_barrier(0);

  float bz[4];
#pragma unroll
  for (int fn = 0; fn < 4; ++fn)
    bz[fn] = BIAS ? bias2[bx * NC + n0 + wc * 64 + fn * 16 + (l & 15)] : 0.f;

  float sv[4], qv[4];
#pragma unroll
  for (int fn = 0; fn < 4; ++fn) {
    float s = 0.f, q = 0.f;
#pragma unroll
    for (int fm = 0; fm < 8; ++fm)
#pragma unroll
      for (int j = 0; j < 4; ++j) {
        float v = acc[fm][fn][j] + bz[fn];
        acc[fm][fn][j] = v;
        s += v;
        q = fmaf(v, v, q);
      }
    s += __shfl_xor(s, 16); s += __shfl_xor(s, 32);
    q += __shfl_xor(q, 16); q += __shfl_xor(q, 32);
    sv[fn] = s; qv[fn] = q;
  }
  if (l < 16) {
    int mb = bx * 2 + wr;  // 128-row chunk id (0..31)
    float2* pp = part + ((size_t)g * 32 + mb) * NC + n0 + wc * 64 + l;
#pragma unroll
    for (int fn = 0; fn < 4; ++fn) pp[fn * 16] = make_float2(sv[fn], qv[fn]);
  }

  ushort* ep = &lds[w * 1088];  // 16 x 68 per wave
  ushort* Hg = H + ((size_t)g * MF + m0 + wr * 128) * NC + n0 + wc * 64;
#pragma unroll
  for (int fm = 0; fm < 8; ++fm) {
#pragma unroll
    for (int fn = 0; fn < 4; ++fn)
#pragma unroll
      for (int j = 0; j < 4; ++j)
        ep[((l >> 4) * 4 + j) * 68 + fn * 16 + (l & 15)] = f2b(acc[fm][fn][j]);
#pragma unroll
    for (int h = 0; h < 2; ++h) {
      int r = h * 8 + (l >> 3), sl = l & 7;
      short8 v = *(const short8*)&ep[r * 68 + sl * 8];
      *(short8*)&Hg[(size_t)(fm * 16 + r) * NC + sl * 8] = v;
    }
  }
}

// ---------------- stats finalize: (scale, shift) per (g,o) from 32 partials ------
__global__ __launch_bounds__(256) void k_stats2(
    const float2* __restrict__ part, const float* __restrict__ gam,
    const float* __restrict__ bet, float2* __restrict__ st) {
  int bi = blockIdx.x;
  int g = bi >> 1;
  int o = (bi & 1) * 256 + threadIdx.x;
  float s = 0.f, q = 0.f;
#pragma unroll
  for (int mb = 0; mb < 32; ++mb) {
    float2 v = part[((size_t)g * 32 + mb) * NC + o];
    s += v.x;
    q += v.y;
  }
  float mu = s * (1.f / 4096.f);
  float var = q * (1.f / 4096.f) - mu * mu;
  float sc = rsqrtf(var + EPS) * gam[o];
  st[g * NC + o] = make_float2(sc, bet[o] - mu * sc);
}

// ---------------- act: a1 = bf16(lrelu(h1*sc+sh)) --------------------------------
__global__ __launch_bounds__(256) void k_act(
    const ushort* __restrict__ h1, const float2* __restrict__ st,
    ushort* __restrict__ a1) {
  int g = blockIdx.z;
  size_t i0 = ((size_t)blockIdx.x * 256 + threadIdx.x) * 8;
  int o0 = (int)(i0 & 511);
  const ushort* src = h1 + (size_t)g * FRAME_ELEMS + i0;
  ushort* dst = a1 + (size_t)g * FRAME_ELEMS + i0;
  short8 v = *(const short8*)src;
  short8 r;
#pragma unroll
  for (int e = 0; e < 8; ++e) {
    float2 ss = st[g * NC + o0 + e];
    float x = fmaf(b2f((ushort)v[e]), ss.x, ss.y);
    r[e] = (short)f2b(lrelu(x));
  }
  *(short8*)dst = r;
}

// ---------------- conv3: 2x2 stride-2, with inline bn+leaky ----------------------
__global__ __launch_bounds__(256) void k_conv3(
    const ushort* __restrict__ h2, const float2* __restrict__ st2,
    const float* __restrict__ w3, float* __restrict__ out, int f0) {
  int g = blockIdx.z;
  int b = blockIdx.x;
  int t = threadIdx.x;
  int oi = t >> 2;
  int cs = t & 3;
  int y = oi >> 3, x = oi & 7;
  const ushort* base = h2 + ((size_t)g * MF + b * NHW) * NC;
  int m00 = (2 * y) * 16 + 2 * x;
  float acc = 0.f;
  for (int c8 = cs * 128; c8 < cs * 128 + 128; c8 += 8) {
    short8 v0 = *(const short8*)&base[(size_t)(m00 + 0) * NC + c8];
    short8 v1 = *(const short8*)&base[(size_t)(m00 + 1) * NC + c8];
    short8 v2 = *(const short8*)&base[(size_t)(m00 + 16) * NC + c8];
    short8 v3 = *(const short8*)&base[(size_t)(m00 + 17) * NC + c8];
#pragma unroll
    for (int e = 0; e < 8; ++e) {
      float2 ss = st2[g * NC + c8 + e];
      float4 wv = ((const float4*)w3)[c8 + e];
      acc = fmaf(lrelu(fmaf(b2f((ushort)v0[e]), ss.x, ss.y)), wv.x, acc);
      acc = fmaf(lrelu(fmaf(b2f((ushort)v1[e]), ss.x, ss.y)), wv.y, acc);
      acc = fmaf(lrelu(fmaf(b2f((ushort)v2[e]), ss.x, ss.y)), wv.z, acc);
      acc = fmaf(lrelu(fmaf(b2f((ushort)v3[e]), ss.x, ss.y)), wv.w, acc);
    }
  }
  acc += __shfl_xor(acc, 1);
  acc += __shfl_xor(acc, 2);
  if (cs == 0) out[((size_t)(f0 + g) * NBATCH + b) * 64 + oi] = acc;
}

extern "C" void kernel_launch(void* const* d_in, const int* in_sizes, int n_in,
                              void* d_out, int out_size, void* d_ws, size_t ws_size,
                              hipStream_t stream) {
  const float* cond = (const float*)d_in[0];
  const float* xbar = (const float*)d_in[1];
  const float* lin_w = (const float*)d_in[2];
  const float* lin_b = (const float*)d_in[3];
  const float* bnsg = (const float*)d_in[4];
  const float* bnsb = (const float*)d_in[5];
  const float* w1 = (const float*)d_in[6];
  const float* bn1g = (const float*)d_in[7];
  const float* bn1b = (const float*)d_in[8];
  const float* w2 = (const float*)d_in[9];
  const float* bn2g = (const float*)d_in[10];
  const float* bn2b = (const float*)d_in[11];
  const float* w3 = (const float*)d_in[12];
  float* out = (float*)d_out;

  char* p = (char*)d_ws;
  float* sent = (float*)p;    p += ((NBATCH * ND * 4 + 255) & ~255);
  float* bias2 = (float*)p;   p += ((NBATCH * NC * 4 + 255) & ~255);
  float2* st1 = (float2*)p;   p += ((NF * NC * 8 + 255) & ~255);
  float2* st2 = (float2*)p;   p += ((NF * NC * 8 + 255) & ~255);
  float2* part = (float2*)p;  p += (((size_t)NF * 32 * NC * 8 + 255) & ~255);
  ushort* w1b = (ushort*)p;   p += ((NC * NC * 2 + 255) & ~255);
  ushort* w2b = (ushort*)p;   p += ((NC * NC * 2 + 255) & ~255);
  size_t used = (size_t)(p - (char*)d_ws);
  const size_t frame_bytes = FRAME_ELEMS * 2;  // 4.19 MB bf16
  size_t rem = ws_size > used ? ws_size - used : 0;
  int FB = (int)(rem / (3 * frame_bytes));
  if (FB < 1) FB = 1;
  if (FB > NF) FB = NF;
  ushort* bufA = (ushort*)p;                       // mot, then a1 (after gemm1)
  ushort* bufB = bufA + (size_t)FB * FRAME_ELEMS;  // h1
  ushort* bufC = bufB + (size_t)FB * FRAME_ELEMS;  // h2

  k_pre<<<1025, 256, 0, stream>>>(w1, w2, cond, lin_w, lin_b, bnsg, bnsb,
                                  w1b, w2b, sent);

  for (int f0 = 0; f0 < NF; f0 += FB) {
    int nb = (NF - f0) < FB ? (NF - f0) : FB;
    int ngrp = (nb + 7) / 8;
    k_mot<<<dim3(33, NBATCH, ngrp), 256, 0, stream>>>(xbar, bufA, f0, nb,
                                                      sent, w2, bias2);
    k_gemm8<0><<<dim3(16, 2, nb), 512, 0, stream>>>(bufA, w1b, nullptr, bufB, part);
    k_stats2<<<2 * nb, 256, 0, stream>>>(part, bn1g, bn1b, st1);
    k_act<<<dim3(1024, 1, nb), 256, 0, stream>>>(bufB, st1, bufA);
    k_gemm8<1><<<dim3(16, 2, nb), 512, 0, stream>>>(bufA, w2b, bias2, bufC, part);
    k_stats2<<<2 * nb, 256, 0, stream>>>(part, bn2g, bn2b, st2);
    k_conv3<<<dim3(NBATCH, 1, nb), 256, 0, stream>>>(bufC, st2, w3, out, f0);
  }
}

// Round 7
// 262.568 us; speedup vs baseline: 1.7178x; 1.0800x over previous
//
#include <hip/hip_runtime.h>
#include <hip/hip_bf16.h>

#define EPS 1e-5f
#define SLOPE 0.2f

#define NF 16      // frames = T-1
#define NBATCH 16  // batch B
#define NC 512     // channels C (= GEMM N and K)
#define NHW 256    // H*W
#define ND 256     // cond dim D
#define K2 768     // C + D (conv2_w row stride)
#define MF 4096    // per-frame GEMM M = B*HW
#define FRAME_ELEMS ((size_t)MF * NC)   // 2,097,152

typedef __attribute__((ext_vector_type(8))) short short8;
typedef __attribute__((ext_vector_type(4))) float float4v;

__device__ __forceinline__ float lrelu(float v) { return v >= 0.f ? v : SLOPE * v; }
__device__ __forceinline__ float b2f(ushort u) { union { float f; uint i; } x; x.i = ((uint)u) << 16; return x.f; }
__device__ __forceinline__ ushort f2b(float f) {
  uint i = __float_as_uint(f);
  return (ushort)((i + 0x7FFFu + ((i >> 16) & 1u)) >> 16);
}
__device__ __forceinline__ void gl16(const ushort* g, ushort* l) {
  __builtin_amdgcn_global_load_lds(
      (const __attribute__((address_space(1))) unsigned int*)g,
      (__attribute__((address_space(3))) unsigned int*)l, 16, 0, 0);
}

// ---------------- fused prep: weights->bf16 + sent ------------------------------
__global__ __launch_bounds__(256) void k_pre(
    const float* __restrict__ w1, const float* __restrict__ w2,
    const float* __restrict__ cond, const float* __restrict__ lin_w,
    const float* __restrict__ lin_b, const float* __restrict__ gam,
    const float* __restrict__ bet,
    ushort* __restrict__ w1b, ushort* __restrict__ w2b,
    float* __restrict__ sent) {
  int bx = blockIdx.x, t = threadIdx.x;
  if (bx < 1024) {
    int i = bx * 256 + t;
    w1b[i] = f2b(w1[i]);
    int o = i >> 9, c = i & 511;
    w2b[i] = f2b(w2[(size_t)o * K2 + c]);
    return;
  }
  int d = t;
  float acc[NBATCH];
  float bias = lin_b[d];
#pragma unroll
  for (int b = 0; b < NBATCH; ++b) acc[b] = bias;
  for (int k = 0; k < ND; ++k) {
    float w = lin_w[d * ND + k];
#pragma unroll
    for (int b = 0; b < NBATCH; ++b) acc[b] = fmaf(cond[b * ND + k], w, acc[b]);
  }
  float mu = 0.f;
#pragma unroll
  for (int b = 0; b < NBATCH; ++b) mu += acc[b];
  mu *= (1.f / NBATCH);
  float var = 0.f;
#pragma unroll
  for (int b = 0; b < NBATCH; ++b) { float x = acc[b] - mu; var = fmaf(x, x, var); }
  var *= (1.f / NBATCH);
  float sc = rsqrtf(var + EPS) * gam[d];
  float sh = bet[d] - mu * sc;
#pragma unroll
  for (int b = 0; b < NBATCH; ++b) sent[b * ND + d] = lrelu(fmaf(acc[b], sc, sh));
}

// ---------------- motions: diff + transpose + cvt, ONE frame per block -----------
// grid (33, NBATCH, nb): x<32 -> (c0,hw0) patch of frame z; x==32 -> bias2 (z==0)
__global__ __launch_bounds__(256) void k_mot(
    const float* __restrict__ xbar, ushort* __restrict__ mot, int f0, int nb,
    const float* __restrict__ sent, const float* __restrict__ w2,
    float* __restrict__ bias2) {
  int t = threadIdx.x;
  if (blockIdx.x == 32) {
    if (blockIdx.z != 0 || blockIdx.y >= 2) return;
    int o = blockIdx.y * 256 + t;
    float acc[NBATCH];
#pragma unroll
    for (int b = 0; b < NBATCH; ++b) acc[b] = 0.f;
    for (int d = 0; d < ND; ++d) {
      float w = w2[(size_t)o * K2 + NC + d];
#pragma unroll
      for (int b = 0; b < NBATCH; ++b) acc[b] = fmaf(sent[b * ND + d], w, acc[b]);
    }
#pragma unroll
    for (int b = 0; b < NBATCH; ++b) bias2[b * NC + o] = acc[b];
    return;
  }

  __shared__ float T[64][65];
  int b = blockIdx.y;
  int hw0 = (blockIdx.x & 3) * 64;
  int c0 = (blockIdx.x >> 2) * 64;
  int w = t >> 6, l = t & 63;
  int fr = blockIdx.z;

  const float* x0 = xbar + ((size_t)(f0 + fr) * NBATCH + b) * (NC * NHW) + hw0 + l;
  const float* x1 = x0 + (size_t)NBATCH * NC * NHW;
  float d[16];
#pragma unroll
  for (int k = 0; k < 16; ++k) {
    size_t off = (size_t)(c0 + 4 * k + w) * NHW;
    d[k] = x1[off] - x0[off];
  }
#pragma unroll
  for (int k = 0; k < 16; ++k) T[4 * k + w][l] = d[k];
  __syncthreads();
  ushort* mp = mot + ((size_t)fr * MF + b * NHW + hw0) * NC + c0;
#pragma unroll
  for (int k = 0; k < 16; ++k) mp[(size_t)(4 * k + w) * NC + l] = f2b(T[l][4 * k + w]);
}

// ---------------- 256x256 8-wave MFMA GEMM, counted-vmcnt dbuf pipeline ----------
template <int BIAS>
__global__ __launch_bounds__(512, 2) void k_gemm8(
    const ushort* __restrict__ A, const ushort* __restrict__ W,
    const float* __restrict__ bias2, ushort* __restrict__ H,
    float2* __restrict__ part) {
  __shared__ ushort lds[65536];  // [buf][A:16384|B:16384]
  const int t = threadIdx.x, w = t >> 6, l = t & 63;
  const int g = blockIdx.z, bx = blockIdx.x, ny = blockIdx.y;
  const int m0 = bx * 256, n0 = ny * 256;
  const int wr = w >> 2, wc = w & 3;

  const ushort* Ag = A + (size_t)g * FRAME_ELEMS + (size_t)m0 * NC;
  const ushort* Wg = W + (size_t)n0 * NC;

  size_t goff[4];
  int loff[4];
#pragma unroll
  for (int q = 0; q < 4; ++q) {
    int u = w * 256 + q * 64 + l;
    int row = u >> 3, cb = (u & 7) ^ (row & 7);
    goff[q] = (size_t)row * NC + cb * 8;
    loff[q] = u * 8;
  }

#define STAGE8(t_, b_)                                               \
  do {                                                               \
    const int k0_ = (t_) * 64;                                       \
    _Pragma("unroll") for (int q = 0; q < 4; ++q)                    \
        gl16(Ag + goff[q] + k0_, &lds[(b_) * 32768 + loff[q]]);      \
    _Pragma("unroll") for (int q = 0; q < 4; ++q)                    \
        gl16(Wg + goff[q] + k0_, &lds[(b_) * 32768 + 16384 + loff[q]]); \
  } while (0)

  int slot[2];
#pragma unroll
  for (int kk = 0; kk < 2; ++kk) slot[kk] = (((kk * 4 + (l >> 4)) ^ (l & 7)) * 8);

  float4v acc[8][4];
#pragma unroll
  for (int i = 0; i < 8; ++i)
#pragma unroll
    for (int j = 0; j < 4; ++j) acc[i][j] = (float4v)0.f;

  STAGE8(0, 0);
  STAGE8(1, 1);
  asm volatile("s_waitcnt vmcnt(8)" ::: "memory");
  __builtin_amdgcn_sched_barrier(0);
  __builtin_amdgcn_s_barrier();
  __builtin_amdgcn_sched_barrier(0);

#pragma unroll
  for (int kt = 0; kt < 8; ++kt) {
    const int b = kt & 1;
    const ushort* la = &lds[b * 32768];
    const ushort* lb = la + 16384;
    short8 bf[4][2], af[4][2];
#pragma unroll
    for (int fn = 0; fn < 4; ++fn) {
      int r = wc * 64 + fn * 16 + (l & 15);
#pragma unroll
      for (int kk = 0; kk < 2; ++kk)
        bf[fn][kk] = *(const short8*)&lb[r * 64 + slot[kk]];
    }
#pragma unroll
    for (int fm = 0; fm < 4; ++fm) {
      int r = wr * 128 + fm * 16 + (l & 15);
#pragma unroll
      for (int kk = 0; kk < 2; ++kk)
        af[fm][kk] = *(const short8*)&la[r * 64 + slot[kk]];
    }
    asm volatile("s_waitcnt lgkmcnt(0)" ::: "memory");
    __builtin_amdgcn_sched_barrier(0);
    __builtin_amdgcn_s_setprio(1);
#pragma unroll
    for (int kk = 0; kk < 2; ++kk)
#pragma unroll
      for (int fm = 0; fm < 4; ++fm)
#pragma unroll
        for (int fn = 0; fn < 4; ++fn)
          acc[fm][fn] = __builtin_amdgcn_mfma_f32_16x16x32_bf16(
              af[fm][kk], bf[fn][kk], acc[fm][fn], 0, 0, 0);
    __builtin_amdgcn_s_setprio(0);
#pragma unroll
    for (int fm = 0; fm < 4; ++fm) {
      int r = wr * 128 + 64 + fm * 16 + (l & 15);
#pragma unroll
      for (int kk = 0; kk < 2; ++kk)
        af[fm][kk] = *(const short8*)&la[r * 64 + slot[kk]];
    }
    asm volatile("s_waitcnt lgkmcnt(0)" ::: "memory");
    __builtin_amdgcn_sched_barrier(0);
    __builtin_amdgcn_s_barrier();   // all waves done reading buf b
    __builtin_amdgcn_sched_barrier(0);
    if (kt < 6) STAGE8(kt + 2, b);
    __builtin_amdgcn_s_setprio(1);
#pragma unroll
    for (int kk = 0; kk < 2; ++kk)
#pragma unroll
      for (int fm = 0; fm < 4; ++fm)
#pragma unroll
        for (int fn = 0; fn < 4; ++fn)
          acc[fm + 4][fn] = __builtin_amdgcn_mfma_f32_16x16x32_bf16(
              af[fm][kk], bf[fn][kk], acc[fm + 4][fn], 0, 0, 0);
    __builtin_amdgcn_s_setprio(0);
    if (kt < 7) {
      if (kt < 6) asm volatile("s_waitcnt vmcnt(8)" ::: "memory");
      else        asm volatile("s_waitcnt vmcnt(0)" ::: "memory");
      __builtin_amdgcn_sched_barrier(0);
      __builtin_amdgcn_s_barrier();
      __builtin_amdgcn_sched_barrier(0);
    }
  }
#undef STAGE8

  __builtin_amdgcn_sched_barrier(0);
  __builtin_amdgcn_s_barrier();
  __builtin_amdgcn_sched_barrier(0);

  float bz[4];
#pragma unroll
  for (int fn = 0; fn < 4; ++fn)
    bz[fn] = BIAS ? bias2[bx * NC + n0 + wc * 64 + fn * 16 + (l & 15)] : 0.f;

  float sv[4], qv[4];
#pragma unroll
  for (int fn = 0; fn < 4; ++fn) {
    float s = 0.f, q = 0.f;
#pragma unroll
    for (int fm = 0; fm < 8; ++fm)
#pragma unroll
      for (int j = 0; j < 4; ++j) {
        float v = acc[fm][fn][j] + bz[fn];
        acc[fm][fn][j] = v;
        s += v;
        q = fmaf(v, v, q);
      }
    s += __shfl_xor(s, 16); s += __shfl_xor(s, 32);
    q += __shfl_xor(q, 16); q += __shfl_xor(q, 32);
    sv[fn] = s; qv[fn] = q;
  }
  if (l < 16) {
    int mb = bx * 2 + wr;
    float2* pp = part + ((size_t)g * 32 + mb) * NC + n0 + wc * 64 + l;
#pragma unroll
    for (int fn = 0; fn < 4; ++fn) pp[fn * 16] = make_float2(sv[fn], qv[fn]);
  }

  ushort* ep = &lds[w * 1088];  // 16 x 68 per wave
  ushort* Hg = H + ((size_t)g * MF + m0 + wr * 128) * NC + n0 + wc * 64;
#pragma unroll
  for (int fm = 0; fm < 8; ++fm) {
#pragma unroll
    for (int fn = 0; fn < 4; ++fn)
#pragma unroll
      for (int j = 0; j < 4; ++j)
        ep[((l >> 4) * 4 + j) * 68 + fn * 16 + (l & 15)] = f2b(acc[fm][fn][j]);
#pragma unroll
    for (int h = 0; h < 2; ++h) {
      int r = h * 8 + (l >> 3), sl = l & 7;
      short8 v = *(const short8*)&ep[r * 68 + sl * 8];
      *(short8*)&Hg[(size_t)(fm * 16 + r) * NC + sl * 8] = v;
    }
  }
}

// ---------------- stats finalize: (scale, shift) per (g,o) from 32 partials ------
__global__ __launch_bounds__(256) void k_stats2(
    const float2* __restrict__ part, const float* __restrict__ gam,
    const float* __restrict__ bet, float2* __restrict__ st) {
  int bi = blockIdx.x;
  int g = bi >> 1;
  int o = (bi & 1) * 256 + threadIdx.x;
  float s = 0.f, q = 0.f;
#pragma unroll
  for (int mb = 0; mb < 32; ++mb) {
    float2 v = part[((size_t)g * 32 + mb) * NC + o];
    s += v.x;
    q += v.y;
  }
  float mu = s * (1.f / 4096.f);
  float var = q * (1.f / 4096.f) - mu * mu;
  float sc = rsqrtf(var + EPS) * gam[o];
  st[g * NC + o] = make_float2(sc, bet[o] - mu * sc);
}

// ---------------- act: a1 = bf16(lrelu(h1*sc+sh)) --------------------------------
__global__ __launch_bounds__(256) void k_act(
    const ushort* __restrict__ h1, const float2* __restrict__ st,
    ushort* __restrict__ a1) {
  int g = blockIdx.z;
  size_t i0 = ((size_t)blockIdx.x * 256 + threadIdx.x) * 8;
  int o0 = (int)(i0 & 511);
  const ushort* src = h1 + (size_t)g * FRAME_ELEMS + i0;
  ushort* dst = a1 + (size_t)g * FRAME_ELEMS + i0;
  short8 v = *(const short8*)src;
  short8 r;
#pragma unroll
  for (int e = 0; e < 8; ++e) {
    float2 ss = st[g * NC + o0 + e];
    float x = fmaf(b2f((ushort)v[e]), ss.x, ss.y);
    r[e] = (short)f2b(lrelu(x));
  }
  *(short8*)dst = r;
}

// ---------------- conv3: 2x2 stride-2, inline bn+leaky, 16-lane channel split ----
// grid (NBATCH*4, 1, nb): block = 16 output pixels of one (f,b); t>>4 = pixel,
// t&15 = 32-channel slice; 4-step shfl reduce over the 16 lanes.
__global__ __launch_bounds__(256) void k_conv3(
    const ushort* __restrict__ h2, const float2* __restrict__ st2,
    const float* __restrict__ w3, float* __restrict__ out, int f0) {
  int g = blockIdx.z;
  int b = blockIdx.x >> 2;
  int q = blockIdx.x & 3;
  int t = threadIdx.x;
  int oi = q * 16 + (t >> 4);
  int cs = t & 15;
  int y = oi >> 3, x = oi & 7;
  const ushort* base = h2 + ((size_t)g * MF + b * NHW) * NC;
  int m00 = (2 * y) * 16 + 2 * x;
  float acc = 0.f;
#pragma unroll
  for (int c8 = cs * 32; c8 < cs * 32 + 32; c8 += 8) {
    short8 v0 = *(const short8*)&base[(size_t)(m00 + 0) * NC + c8];
    short8 v1 = *(const short8*)&base[(size_t)(m00 + 1) * NC + c8];
    short8 v2 = *(const short8*)&base[(size_t)(m00 + 16) * NC + c8];
    short8 v3 = *(const short8*)&base[(size_t)(m00 + 17) * NC + c8];
#pragma unroll
    for (int e = 0; e < 8; ++e) {
      float2 ss = st2[g * NC + c8 + e];
      float4 wv = ((const float4*)w3)[c8 + e];
      acc = fmaf(lrelu(fmaf(b2f((ushort)v0[e]), ss.x, ss.y)), wv.x, acc);
      acc = fmaf(lrelu(fmaf(b2f((ushort)v1[e]), ss.x, ss.y)), wv.y, acc);
      acc = fmaf(lrelu(fmaf(b2f((ushort)v2[e]), ss.x, ss.y)), wv.z, acc);
      acc = fmaf(lrelu(fmaf(b2f((ushort)v3[e]), ss.x, ss.y)), wv.w, acc);
    }
  }
  acc += __shfl_xor(acc, 1);
  acc += __shfl_xor(acc, 2);
  acc += __shfl_xor(acc, 4);
  acc += __shfl_xor(acc, 8);
  if (cs == 0) out[((size_t)(f0 + g) * NBATCH + b) * 64 + oi] = acc;
}

extern "C" void kernel_launch(void* const* d_in, const int* in_sizes, int n_in,
                              void* d_out, int out_size, void* d_ws, size_t ws_size,
                              hipStream_t stream) {
  const float* cond = (const float*)d_in[0];
  const float* xbar = (const float*)d_in[1];
  const float* lin_w = (const float*)d_in[2];
  const float* lin_b = (const float*)d_in[3];
  const float* bnsg = (const float*)d_in[4];
  const float* bnsb = (const float*)d_in[5];
  const float* w1 = (const float*)d_in[6];
  const float* bn1g = (const float*)d_in[7];
  const float* bn1b = (const float*)d_in[8];
  const float* w2 = (const float*)d_in[9];
  const float* bn2g = (const float*)d_in[10];
  const float* bn2b = (const float*)d_in[11];
  const float* w3 = (const float*)d_in[12];
  float* out = (float*)d_out;

  char* p = (char*)d_ws;
  float* sent = (float*)p;    p += ((NBATCH * ND * 4 + 255) & ~255);
  float* bias2 = (float*)p;   p += ((NBATCH * NC * 4 + 255) & ~255);
  float2* st1 = (float2*)p;   p += ((NF * NC * 8 + 255) & ~255);
  float2* st2 = (float2*)p;   p += ((NF * NC * 8 + 255) & ~255);
  float2* part = (float2*)p;  p += (((size_t)NF * 32 * NC * 8 + 255) & ~255);
  ushort* w1b = (ushort*)p;   p += ((NC * NC * 2 + 255) & ~255);
  ushort* w2b = (ushort*)p;   p += ((NC * NC * 2 + 255) & ~255);
  size_t used = (size_t)(p - (char*)d_ws);
  const size_t frame_bytes = FRAME_ELEMS * 2;  // 4.19 MB bf16
  size_t rem = ws_size > used ? ws_size - used : 0;
  int FB = (int)(rem / (3 * frame_bytes));
  if (FB < 1) FB = 1;
  if (FB > NF) FB = NF;
  ushort* bufA = (ushort*)p;                       // mot, then a1 (after gemm1)
  ushort* bufB = bufA + (size_t)FB * FRAME_ELEMS;  // h1
  ushort* bufC = bufB + (size_t)FB * FRAME_ELEMS;  // h2

  k_pre<<<1025, 256, 0, stream>>>(w1, w2, cond, lin_w, lin_b, bnsg, bnsb,
                                  w1b, w2b, sent);

  for (int f0 = 0; f0 < NF; f0 += FB) {
    int nb = (NF - f0) < FB ? (NF - f0) : FB;
    k_mot<<<dim3(33, NBATCH, nb), 256, 0, stream>>>(xbar, bufA, f0, nb,
                                                    sent, w2, bias2);
    k_gemm8<0><<<dim3(16, 2, nb), 512, 0, stream>>>(bufA, w1b, nullptr, bufB, part);
    k_stats2<<<2 * nb, 256, 0, stream>>>(part, bn1g, bn1b, st1);
    k_act<<<dim3(1024, 1, nb), 256, 0, stream>>>(bufB, st1, bufA);
    k_gemm8<1><<<dim3(16, 2, nb), 512, 0, stream>>>(bufA, w2b, bias2, bufC, part);
    k_stats2<<<2 * nb, 256, 0, stream>>>(part, bn2g, bn2b, st2);
    k_conv3<<<dim3(NBATCH * 4, 1, nb), 256, 0, stream>>>(bufC, st2, w3, out, f0);
  }
}